// Round 1
// baseline (1002.776 us; speedup 1.0000x reference)
//
#include <hip/hip_runtime.h>
#include <math.h>

#define SRATE   44100
#define HOPSZ   512
#define NFFT    2048
#define PADW    1024
#define NBINS   540
#define NFRAMES 431
#define NSAMP   220500
#define NBATCH  16
#define FBLK    32
#define ASTRIDE 1456            // complex elems per bin (max nk=1454, padded to mult of 8)
#define KGROUPS 6
#define TABOFF  2048            // float offset of atom table in ws (8192 bytes header)
#define XS_RAW  ((FBLK-1)*HOPSZ + NFFT)          // 17920
#define XS_PAD  (XS_RAW + (XS_RAW >> 9))          // 17955 floats, 71.8 KB

#define PI_D 3.14159265358979323846

// ---------------------------------------------------------------------------
// Build conjugated, windowed, l1-normalized, scale-folded atoms into d_ws.
// Layout: int2 hdr[NBINS] at byte 0 {nk8, s}; float table at byte 8192,
// bin k at TABOFF + k*ASTRIDE*2, interleaved (re,im), zero-padded to nk8.
// ---------------------------------------------------------------------------
__global__ void build_atoms(float* __restrict__ ws) {
    int k = blockIdx.x;
    double freq  = 27.5 * exp2((double)k / 60.0);
    double r     = exp2(2.0 / 60.0);
    double alpha = (r - 1.0) / (r + 1.0);
    double len   = (1.0 / alpha) * (double)SRATE / (freq + 30.0 / alpha);
    int nk  = (int)floor(len);
    int s   = (NFFT - nk) / 2;
    int nk8 = (nk + 7) & ~7;
    float* tab = ws + TABOFF + (size_t)k * (ASTRIDE * 2);
    // norm = 1/sum(hann) = 2/(nk-1); scale = 1/sqrt(len)
    double amp = (2.0 / (double)(nk - 1)) * (1.0 / sqrt(len));
    for (int t = threadIdx.x; t < ASTRIDE; t += blockDim.x) {
        float cre = 0.f, cim = 0.f;
        if (t < nk) {
            double w  = 0.5 - 0.5 * cos(2.0 * PI_D * (double)t / (double)(nk - 1));
            double ph = fmod(2.0 * freq * (double)t / (double)SRATE, 2.0); // units of pi
            double sp, cp;
            sincospi(ph, &sp, &cp);
            double a = w * amp;
            cre = (float)(a * cp);
            cim = (float)(-a * sp);   // conj (sign irrelevant for |.| but keep exact)
        }
        tab[2 * t]     = cre;
        tab[2 * t + 1] = cim;
    }
    if (threadIdx.x == 0) {
        ((int2*)ws)[k] = make_int2(nk8, s);
    }
}

// ---------------------------------------------------------------------------
// Main: block = 512 thr, covers (batch b, 32 frames, k ≡ kg mod KGROUPS).
// Half-wave (32 lanes) = 32 frames × one bin; atoms from global (L1/L2),
// x window staged in LDS with +1-per-512 padding (conflict-free strided read).
// ---------------------------------------------------------------------------
__global__ __launch_bounds__(512, 2) void vqt_main(const float* __restrict__ x,
                                                   const float* __restrict__ ws,
                                                   float* __restrict__ out) {
    __shared__ float xs[XS_PAD];
    const int b  = blockIdx.z;
    const int f0 = blockIdx.x * FBLK;
    const int kg = blockIdx.y;

    // ---- stage x window: xp indices [f0*512, f0*512+17920) ; xp = x padded by 1024
    const float* xb = x + (size_t)b * NSAMP;
    const int base = f0 * HOPSZ - PADW;           // global x index of xs[0]
    for (int i4 = threadIdx.x; i4 < XS_RAW / 4; i4 += blockDim.x) {
        int i = i4 * 4;
        int g = base + i;
        float4 v;
        if (g >= 0 && g + 3 < NSAMP) {
            v = *(const float4*)(xb + g);
        } else {
            v.x = (g + 0 >= 0 && g + 0 < NSAMP) ? xb[g + 0] : 0.f;
            v.y = (g + 1 >= 0 && g + 1 < NSAMP) ? xb[g + 1] : 0.f;
            v.z = (g + 2 >= 0 && g + 2 < NSAMP) ? xb[g + 2] : 0.f;
            v.w = (g + 3 >= 0 && g + 3 < NSAMP) ? xb[g + 3] : 0.f;
        }
        int a = i + (i >> 9);
        xs[a + 0] = v.x; xs[a + 1] = v.y; xs[a + 2] = v.z; xs[a + 3] = v.w;
    }
    __syncthreads();

    const int tid   = threadIdx.x;
    const int lane  = tid & 63;
    const int wid   = tid >> 6;       // 0..7
    const int ksub  = lane >> 5;      // 0/1
    const int fi    = lane & 31;
    const int frame = f0 + fi;

    const int2*  hdr     = (const int2*)ws;
    const float* tabbase = ws + TABOFF;
    const int    slot    = wid * 2 + ksub;   // 0..15

    for (int kk = slot; kg + KGROUPS * kk < NBINS; kk += 16) {
        const int k = kg + KGROUPS * kk;
        const int2 h = hdr[k];
        const int nk8 = h.x, s = h.y;
        const float* at = tabbase + (size_t)k * (ASTRIDE * 2);
        const int ib = fi * HOPSZ + s;

        float are0 = 0.f, aim0 = 0.f, are1 = 0.f, aim1 = 0.f;
        for (int t = 0; t < nk8; t += 8) {
            const float4 a0 = *(const float4*)(at + 2 * t);
            const float4 a1 = *(const float4*)(at + 2 * t + 4);
            const float4 a2 = *(const float4*)(at + 2 * t + 8);
            const float4 a3 = *(const float4*)(at + 2 * t + 12);
            const int i = ib + t;
            const float x0 = xs[i     + ((i    ) >> 9)];
            const float x1 = xs[i + 1 + ((i + 1) >> 9)];
            const float x2 = xs[i + 2 + ((i + 2) >> 9)];
            const float x3 = xs[i + 3 + ((i + 3) >> 9)];
            const float x4 = xs[i + 4 + ((i + 4) >> 9)];
            const float x5 = xs[i + 5 + ((i + 5) >> 9)];
            const float x6 = xs[i + 6 + ((i + 6) >> 9)];
            const float x7 = xs[i + 7 + ((i + 7) >> 9)];
            are0 = fmaf(x0, a0.x, are0); aim0 = fmaf(x0, a0.y, aim0);
            are1 = fmaf(x1, a0.z, are1); aim1 = fmaf(x1, a0.w, aim1);
            are0 = fmaf(x2, a1.x, are0); aim0 = fmaf(x2, a1.y, aim0);
            are1 = fmaf(x3, a1.z, are1); aim1 = fmaf(x3, a1.w, aim1);
            are0 = fmaf(x4, a2.x, are0); aim0 = fmaf(x4, a2.y, aim0);
            are1 = fmaf(x5, a2.z, are1); aim1 = fmaf(x5, a2.w, aim1);
            are0 = fmaf(x6, a3.x, are0); aim0 = fmaf(x6, a3.y, aim0);
            are1 = fmaf(x7, a3.z, are1); aim1 = fmaf(x7, a3.w, aim1);
        }
        if (frame < NFRAMES) {
            const float are = are0 + are1, aim = aim0 + aim1;
            out[((size_t)b * NFRAMES + frame) * NBINS + k] =
                sqrtf(are * are + aim * aim);
        }
    }
}

// ---------------------------------------------------------------------------
// Fallback (ws too small): compute atom on the fly with sincos recurrences.
// ---------------------------------------------------------------------------
__global__ __launch_bounds__(512, 2) void vqt_fly(const float* __restrict__ x,
                                                  float* __restrict__ out) {
    __shared__ float xs[XS_PAD];
    const int b  = blockIdx.z;
    const int f0 = blockIdx.x * FBLK;
    const int kg = blockIdx.y;

    const float* xb = x + (size_t)b * NSAMP;
    const int base = f0 * HOPSZ - PADW;
    for (int i4 = threadIdx.x; i4 < XS_RAW / 4; i4 += blockDim.x) {
        int i = i4 * 4;
        int g = base + i;
        float4 v;
        if (g >= 0 && g + 3 < NSAMP) {
            v = *(const float4*)(xb + g);
        } else {
            v.x = (g + 0 >= 0 && g + 0 < NSAMP) ? xb[g + 0] : 0.f;
            v.y = (g + 1 >= 0 && g + 1 < NSAMP) ? xb[g + 1] : 0.f;
            v.z = (g + 2 >= 0 && g + 2 < NSAMP) ? xb[g + 2] : 0.f;
            v.w = (g + 3 >= 0 && g + 3 < NSAMP) ? xb[g + 3] : 0.f;
        }
        int a = i + (i >> 9);
        xs[a + 0] = v.x; xs[a + 1] = v.y; xs[a + 2] = v.z; xs[a + 3] = v.w;
    }
    __syncthreads();

    const int tid   = threadIdx.x;
    const int lane  = tid & 63;
    const int wid   = tid >> 6;
    const int ksub  = lane >> 5;
    const int fi    = lane & 31;
    const int frame = f0 + fi;
    const int slot  = wid * 2 + ksub;

    for (int kk = slot; kg + KGROUPS * kk < NBINS; kk += 16) {
        const int k = kg + KGROUPS * kk;
        double freq  = 27.5 * exp2((double)k / 60.0);
        double r     = exp2(2.0 / 60.0);
        double alpha = (r - 1.0) / (r + 1.0);
        double len   = (1.0 / alpha) * (double)SRATE / (freq + 30.0 / alpha);
        int nk = (int)floor(len);
        int s  = (NFFT - nk) / 2;
        float amp = (float)((2.0 / (double)(nk - 1)) * (1.0 / sqrt(len)));
        double th  = 2.0 * PI_D * freq / (double)SRATE;
        float cth = (float)cos(th),  sth = (float)sin(th);
        double phd = 2.0 * PI_D / (double)(nk - 1);
        float cph = (float)cos(phd), sph = (float)sin(phd);

        float cr = 1.f, si = 0.f, cw = 1.f, sw = 0.f;
        float are = 0.f, aim = 0.f;
        const int ib = fi * HOPSZ + s;
        for (int t = 0; t < nk; ++t) {
            const int i = ib + t;
            const float xv = xs[i + (i >> 9)];
            const float w  = fmaf(-0.5f, cw, 0.5f);
            const float xw = xv * w;
            are = fmaf(xw, cr, are);
            aim = fmaf(xw, si, aim);
            const float crn = fmaf(cr, cth, -(si * sth));
            const float sin_ = fmaf(si, cth,  cr * sth);
            const float cwn = fmaf(cw, cph, -(sw * sph));
            const float swn = fmaf(sw, cph,  cw * sph);
            cr = crn; si = sin_; cw = cwn; sw = swn;
        }
        if (frame < NFRAMES) {
            out[((size_t)b * NFRAMES + frame) * NBINS + k] =
                sqrtf(are * are + aim * aim) * amp;
        }
    }
}

extern "C" void kernel_launch(void* const* d_in, const int* in_sizes, int n_in,
                              void* d_out, int out_size, void* d_ws, size_t ws_size,
                              hipStream_t stream) {
    const float* x = (const float*)d_in[0];
    float* out = (float*)d_out;
    const size_t need = 8192 + (size_t)NBINS * ASTRIDE * 8;
    const dim3 grid((NFRAMES + FBLK - 1) / FBLK, KGROUPS, NBATCH);
    if (ws_size >= need) {
        build_atoms<<<dim3(NBINS), dim3(256), 0, stream>>>((float*)d_ws);
        vqt_main<<<grid, dim3(512), 0, stream>>>(x, (const float*)d_ws, out);
    } else {
        vqt_fly<<<grid, dim3(512), 0, stream>>>(x, out);
    }
}

// Round 2
// 163.992 us; speedup vs baseline: 6.1148x; 6.1148x over previous
//
#include <hip/hip_runtime.h>
#include <hip/hip_bf16.h>
#include <math.h>

#define SRATE   44100
#define HOPSZ   512
#define NFFT    2048
#define PADW    1024
#define NBINS   540
#define NPADB   544                 // bins padded to multiple of 32
#define NCOLS   1088                // 2*NPADB (re/im interleaved columns)
#define NFRAMES 431
#define NSAMP   220500
#define NBATCH  16

#define BM 64
#define BN 64
#define BK 64
#define MTILES 7                    // ceil(431/64)
#define NTILES 17                   // 1088/64
#define APITCH 72                   // LDS row pitch in bf16 (64 + 8 pad -> +16B/row)

#define PI_D 3.14159265358979323846

typedef __attribute__((ext_vector_type(8))) short short8;
typedef __attribute__((ext_vector_type(4))) float f32x4;

// ---------------------------------------------------------------------------
// Build bf16 atom table in ws: layout [n][k], n = 2*bin + (0=re,1=im),
// k in [0,2048). Conjugated, hann-windowed, l1-normalized, scale-folded,
// zero outside support. Rows for dummy bins (540..543) are zeroed.
// ---------------------------------------------------------------------------
__global__ void build_tab(__hip_bfloat16* __restrict__ tab) {
    const int bin = blockIdx.x;                       // 0..543
    __hip_bfloat16* rowre = tab + (size_t)(2 * bin) * NFFT;
    __hip_bfloat16* rowim = rowre + NFFT;
    if (bin >= NBINS) {
        const __hip_bfloat16 z = __float2bfloat16(0.f);
        for (int t = threadIdx.x; t < NFFT; t += blockDim.x) {
            rowre[t] = z; rowim[t] = z;
        }
        return;
    }
    const double freq  = 27.5 * exp2((double)bin / 60.0);
    const double r     = exp2(2.0 / 60.0);
    const double alpha = (r - 1.0) / (r + 1.0);
    const double len   = (1.0 / alpha) * (double)SRATE / (freq + 30.0 / alpha);
    const int    nk    = (int)floor(len);
    const int    s     = (NFFT - nk) / 2;
    const double amp   = (2.0 / (double)(nk - 1)) / sqrt(len);  // l1 norm * scale
    for (int t = threadIdx.x; t < NFFT; t += blockDim.x) {
        float re = 0.f, im = 0.f;
        const int tp = t - s;
        if (tp >= 0 && tp < nk) {
            const double w  = 0.5 - 0.5 * cos(2.0 * PI_D * (double)tp / (double)(nk - 1));
            const double ph = fmod(2.0 * freq * (double)tp / (double)SRATE, 2.0);
            double sp, cp;
            sincospi(ph, &sp, &cp);
            re = (float)(w * amp * cp);
            im = (float)(-w * amp * sp);              // conj
        }
        rowre[t] = __float2bfloat16(re);
        rowim[t] = __float2bfloat16(im);
    }
}

// ---------------------------------------------------------------------------
// GEMM: C[b, f, n] = sum_k xp[b, f*512 + k] * tab[n][k], then magnitude of
// (re,im) column pairs -> out. Block = 256 thr (4 waves, 2x2), tile 64x64,
// BK=64. A reg-staged from fp32 x (bounds check = implicit zero pad).
// K-loop clipped to the support of the tile's lowest (longest) bin.
// ---------------------------------------------------------------------------
__global__ __launch_bounds__(256) void vqt_gemm(const float* __restrict__ x,
                                                const __hip_bfloat16* __restrict__ tab,
                                                float* __restrict__ out) {
    __shared__ __hip_bfloat16 As[BM * APITCH];
    __shared__ __hip_bfloat16 Bs[BN * APITCH];

    const int mt = blockIdx.x, nt = blockIdx.y, b = blockIdx.z;
    const int n0 = nt * BN;

    // K range from the tile's first bin (longest support; others nested).
    const int    bin0  = n0 >> 1;
    const double freq  = 27.5 * exp2((double)bin0 / 60.0);
    const double r     = exp2(2.0 / 60.0);
    const double alpha = (r - 1.0) / (r + 1.0);
    const double len   = (1.0 / alpha) * (double)SRATE / (freq + 30.0 / alpha);
    const int    nk    = (int)floor(len);
    const int    s     = (NFFT - nk) / 2;
    const int    k0    = s & ~(BK - 1);
    int          k1    = (s + nk + BK - 1) & ~(BK - 1);
    if (k1 > NFFT) k1 = NFFT;

    const int tid  = threadIdx.x;
    const int lane = tid & 63;
    const int wid  = tid >> 6;
    const int wr   = wid >> 1, wc = wid & 1;          // wave -> 32x32 quadrant
    const int sr   = tid >> 2, sq = tid & 3;          // staging row / 16-elem quarter

    const float* xb     = x + (size_t)b * NSAMP;
    const int    f_base = mt * BM;
    // A source: frame (f_base+sr), x index = f*512 - 1024 + kt + sq*16 + ...
    const long arow_off = (long)(f_base + sr) * HOPSZ - PADW + sq * 16;
    const __hip_bfloat16* brow = tab + (size_t)(n0 + sr) * NFFT + sq * 16;

    f32x4 acc[2][2] = {};

    for (int kt = k0; kt < k1; kt += BK) {
        // ---- stage A: 16 fp32 -> 16 bf16 -> 2x ds_write_b128
        union { short8 v[2]; unsigned short u[16]; float4 f4[0]; } pk;
        #pragma unroll
        for (int v = 0; v < 4; ++v) {
            const long g = arow_off + kt + v * 4;     // always 0 mod 4; NSAMP%4==0
            float4 t4 = {0.f, 0.f, 0.f, 0.f};
            if (g >= 0 && g + 4 <= (long)NSAMP) t4 = *(const float4*)(xb + g);
            __hip_bfloat16 h0 = __float2bfloat16(t4.x);
            __hip_bfloat16 h1 = __float2bfloat16(t4.y);
            __hip_bfloat16 h2 = __float2bfloat16(t4.z);
            __hip_bfloat16 h3 = __float2bfloat16(t4.w);
            pk.u[4 * v + 0] = *(unsigned short*)&h0;
            pk.u[4 * v + 1] = *(unsigned short*)&h1;
            pk.u[4 * v + 2] = *(unsigned short*)&h2;
            pk.u[4 * v + 3] = *(unsigned short*)&h3;
        }
        {
            short8* dst = (short8*)(As + sr * APITCH + sq * 16);
            dst[0] = pk.v[0];
            dst[1] = pk.v[1];
        }
        // ---- stage B: 32B bf16 copy
        {
            const short8* src = (const short8*)(brow + kt);
            short8* dst = (short8*)(Bs + sr * APITCH + sq * 16);
            dst[0] = src[0];
            dst[1] = src[1];
        }
        __syncthreads();

        #pragma unroll
        for (int ks = 0; ks < 2; ++ks) {
            const int kc = ks * 32 + (lane >> 4) * 8;
            const short8 a0 = *(const short8*)(As + (wr * 32 +      (lane & 15)) * APITCH + kc);
            const short8 a1 = *(const short8*)(As + (wr * 32 + 16 + (lane & 15)) * APITCH + kc);
            const short8 b0 = *(const short8*)(Bs + (wc * 32 +      (lane & 15)) * APITCH + kc);
            const short8 b1 = *(const short8*)(Bs + (wc * 32 + 16 + (lane & 15)) * APITCH + kc);
            acc[0][0] = __builtin_amdgcn_mfma_f32_16x16x32_bf16(a0, b0, acc[0][0], 0, 0, 0);
            acc[0][1] = __builtin_amdgcn_mfma_f32_16x16x32_bf16(a0, b1, acc[0][1], 0, 0, 0);
            acc[1][0] = __builtin_amdgcn_mfma_f32_16x16x32_bf16(a1, b0, acc[1][0], 0, 0, 0);
            acc[1][1] = __builtin_amdgcn_mfma_f32_16x16x32_bf16(a1, b1, acc[1][1], 0, 0, 0);
        }
        __syncthreads();
    }

    // ---- epilogue: adjacent cols (even=re, odd=im) live in adjacent lanes
    const int colc = lane & 15, rg = lane >> 4;
    float* outb = out + (size_t)b * NFRAMES * NBINS;
    #pragma unroll
    for (int i = 0; i < 2; ++i) {
        #pragma unroll
        for (int j = 0; j < 2; ++j) {
            #pragma unroll
            for (int reg = 0; reg < 4; ++reg) {
                const float v = acc[i][j][reg];
                const float p = __shfl_xor(v, 1);
                if (!(lane & 1)) {
                    const int f   = f_base + wr * 32 + i * 16 + rg * 4 + reg;
                    const int col = n0 + wc * 32 + j * 16 + colc;
                    const int bin = col >> 1;
                    if (f < NFRAMES && bin < NBINS)
                        outb[(size_t)f * NBINS + bin] = sqrtf(v * v + p * p);
                }
            }
        }
    }
}

// ---------------------------------------------------------------------------
// Fallback (ws too small): on-the-fly sincos recurrence version (round-1).
// ---------------------------------------------------------------------------
#define FBLK 32
#define KGROUPS 6
#define XS_RAW  ((FBLK - 1) * HOPSZ + NFFT)
#define XS_PAD  (XS_RAW + (XS_RAW >> 9))

__global__ __launch_bounds__(512, 2) void vqt_fly(const float* __restrict__ x,
                                                  float* __restrict__ out) {
    __shared__ float xs[XS_PAD];
    const int b  = blockIdx.z;
    const int f0 = blockIdx.x * FBLK;
    const int kg = blockIdx.y;

    const float* xb = x + (size_t)b * NSAMP;
    const int base = f0 * HOPSZ - PADW;
    for (int i4 = threadIdx.x; i4 < XS_RAW / 4; i4 += blockDim.x) {
        int i = i4 * 4;
        int g = base + i;
        float4 v;
        if (g >= 0 && g + 3 < NSAMP) {
            v = *(const float4*)(xb + g);
        } else {
            v.x = (g + 0 >= 0 && g + 0 < NSAMP) ? xb[g + 0] : 0.f;
            v.y = (g + 1 >= 0 && g + 1 < NSAMP) ? xb[g + 1] : 0.f;
            v.z = (g + 2 >= 0 && g + 2 < NSAMP) ? xb[g + 2] : 0.f;
            v.w = (g + 3 >= 0 && g + 3 < NSAMP) ? xb[g + 3] : 0.f;
        }
        int a = i + (i >> 9);
        xs[a + 0] = v.x; xs[a + 1] = v.y; xs[a + 2] = v.z; xs[a + 3] = v.w;
    }
    __syncthreads();

    const int tid   = threadIdx.x;
    const int lane  = tid & 63;
    const int wid   = tid >> 6;
    const int ksub  = lane >> 5;
    const int fi    = lane & 31;
    const int frame = f0 + fi;
    const int slot  = wid * 2 + ksub;

    for (int kk = slot; kg + KGROUPS * kk < NBINS; kk += 16) {
        const int k = kg + KGROUPS * kk;
        double freq  = 27.5 * exp2((double)k / 60.0);
        double r     = exp2(2.0 / 60.0);
        double alpha = (r - 1.0) / (r + 1.0);
        double len   = (1.0 / alpha) * (double)SRATE / (freq + 30.0 / alpha);
        int nk = (int)floor(len);
        int s  = (NFFT - nk) / 2;
        float amp = (float)((2.0 / (double)(nk - 1)) / sqrt(len));
        double th  = 2.0 * PI_D * freq / (double)SRATE;
        float cth = (float)cos(th),  sth = (float)sin(th);
        double phd = 2.0 * PI_D / (double)(nk - 1);
        float cph = (float)cos(phd), sph = (float)sin(phd);

        float cr = 1.f, si = 0.f, cw = 1.f, sw = 0.f;
        float are = 0.f, aim = 0.f;
        const int ib = fi * HOPSZ + s;
        for (int t = 0; t < nk; ++t) {
            const int i = ib + t;
            const float xv = xs[i + (i >> 9)];
            const float w  = fmaf(-0.5f, cw, 0.5f);
            const float xw = xv * w;
            are = fmaf(xw, cr, are);
            aim = fmaf(xw, si, aim);
            const float crn  = fmaf(cr, cth, -(si * sth));
            const float sin_ = fmaf(si, cth,  cr * sth);
            const float cwn  = fmaf(cw, cph, -(sw * sph));
            const float swn  = fmaf(sw, cph,  cw * sph);
            cr = crn; si = sin_; cw = cwn; sw = swn;
        }
        if (frame < NFRAMES) {
            out[((size_t)b * NFRAMES + frame) * NBINS + k] =
                sqrtf(are * are + aim * aim) * amp;
        }
    }
}

extern "C" void kernel_launch(void* const* d_in, const int* in_sizes, int n_in,
                              void* d_out, int out_size, void* d_ws, size_t ws_size,
                              hipStream_t stream) {
    const float* x = (const float*)d_in[0];
    float* out = (float*)d_out;
    const size_t need = (size_t)NCOLS * NFFT * sizeof(__hip_bfloat16);  // 4.46 MB
    if (ws_size >= need) {
        build_tab<<<dim3(NPADB), dim3(256), 0, stream>>>((__hip_bfloat16*)d_ws);
        vqt_gemm<<<dim3(MTILES, NTILES, NBATCH), dim3(256), 0, stream>>>(
            x, (const __hip_bfloat16*)d_ws, out);
    } else {
        vqt_fly<<<dim3((NFRAMES + FBLK - 1) / FBLK, KGROUPS, NBATCH), dim3(512), 0, stream>>>(x, out);
    }
}

// Round 3
// 53.317 us; speedup vs baseline: 18.8078x; 3.0758x over previous
//
#include <hip/hip_runtime.h>
#include <hip/hip_bf16.h>
#include <math.h>

#define SRATE   44100
#define HOPSZ   512
#define NFFT    2048
#define PADW    1024
#define NBINS   540
#define NFRAMES 431
#define NSAMP   220500
#define NBATCH  16

#define PI_D 3.14159265358979323846

typedef __attribute__((ext_vector_type(8))) short short8;
typedef __attribute__((ext_vector_type(4))) float f32x4;

// ======================= PATH A: flattened-M pipelined GEMM =================
#define MROWS   (NBATCH * NFRAMES)      // 6896
#define BM2     128
#define BN2     128
#define BK2     64
#define MT2     54                      // ceil(6896/128)
#define NT2     9
#define NCOLS2  1152                    // 576 bins padded
#define XPITCH  222552                  // bf16 elems per batch (NSAMP+2048 -> mult 8)
#define XPTOT   (NBATCH * XPITCH)       // 3,560,832 elems
#define NCHUNK  (XPITCH / 8)            // 27819

// ---- x (fp32) -> zero-padded bf16 xp[b][XPITCH] ----------------------------
__global__ void cvt_xp(const float* __restrict__ x, __hip_bfloat16* __restrict__ xp) {
    const int idx = blockIdx.x * blockDim.x + threadIdx.x;   // one 8-elem chunk
    if (idx >= NBATCH * NCHUNK) return;
    const int b  = idx / NCHUNK;
    const int c  = idx - b * NCHUNK;
    const int i0 = c * 8;
    const float* xb = x + (size_t)b * NSAMP;
    const int g0 = i0 - PADW;
    union { short8 v; unsigned short u[8]; } pk;
    if (g0 >= 0 && g0 + 8 <= NSAMP) {
        const float4 f0 = *(const float4*)(xb + g0);
        const float4 f1 = *(const float4*)(xb + g0 + 4);
        const float vv[8] = {f0.x, f0.y, f0.z, f0.w, f1.x, f1.y, f1.z, f1.w};
        #pragma unroll
        for (int e = 0; e < 8; ++e) {
            __hip_bfloat16 h = __float2bfloat16(vv[e]);
            pk.u[e] = *(unsigned short*)&h;
        }
    } else {
        #pragma unroll
        for (int e = 0; e < 8; ++e) {
            const int g = g0 + e;
            const float v = (g >= 0 && g < NSAMP) ? xb[g] : 0.f;
            __hip_bfloat16 h = __float2bfloat16(v);
            pk.u[e] = *(unsigned short*)&h;
        }
    }
    *(short8*)(xp + (size_t)b * XPITCH + i0) = pk.v;
}

// ---- B table, [col][2048] bf16, PRE-SWIZZLED: value(k) stored at chunk
//      (k/8)^(col&7), elem k%8. col = 2*bin + (0=re,1=im). ------------------
__global__ void build_tab_swz(__hip_bfloat16* __restrict__ tab) {
    const int col = blockIdx.x;                       // 0..1151
    const int bin = col >> 1;
    const int ri  = col & 1;
    __hip_bfloat16* row = tab + (size_t)col * NFFT;
    if (bin >= NBINS) {
        const __hip_bfloat16 z = __float2bfloat16(0.f);
        for (int t = threadIdx.x; t < NFFT; t += blockDim.x) row[t] = z;
        return;
    }
    const double freq  = 27.5 * exp2((double)bin / 60.0);
    const double r     = exp2(2.0 / 60.0);
    const double alpha = (r - 1.0) / (r + 1.0);
    const double len   = (1.0 / alpha) * (double)SRATE / (freq + 30.0 / alpha);
    const int    nk    = (int)floor(len);
    const int    s     = (NFFT - nk) / 2;
    const double amp   = (2.0 / (double)(nk - 1)) / sqrt(len);
    const int xr = col & 7;
    for (int t = threadIdx.x; t < NFFT; t += blockDim.x) {
        float val = 0.f;
        const int tp = t - s;
        if (tp >= 0 && tp < nk) {
            const double w  = 0.5 - 0.5 * cos(2.0 * PI_D * (double)tp / (double)(nk - 1));
            const double ph = fmod(2.0 * freq * (double)tp / (double)SRATE, 2.0);
            double sp, cp;
            sincospi(ph, &sp, &cp);
            val = ri ? (float)(-w * amp * sp) : (float)(w * amp * cp);
        }
        const int kpos = ((((t >> 3) ^ xr) & 0xff) << 3) | (t & 7);
        row[kpos] = __float2bfloat16(val);
    }
}

// ---- GEMM: out[row*540+bin] = |sum_k xp_row[k] * atom_col[k]| --------------
__device__ __forceinline__ short8 lds_frag(const char* base, int row, int ko) {
    const int off = (row << 7) + (((ko >> 3) ^ (row & 7)) << 4);
    return *(const short8*)(base + off);
}

__global__ __launch_bounds__(256) void vqt_gemm2(const __hip_bfloat16* __restrict__ xp,
                                                 const __hip_bfloat16* __restrict__ tab,
                                                 float* __restrict__ out) {
    __shared__ uint4 smem4[4096];                     // 64 KB: [buf][A 16K | B 16K]
    const int mt = blockIdx.x, nt = blockIdx.y;
    const int row0 = mt * BM2;
    const int n0   = nt * BN2;

    // K clip from lowest (longest-support) bin of tile
    const int    bin0  = n0 >> 1;
    const double freq  = 27.5 * exp2((double)bin0 / 60.0);
    const double rr    = exp2(2.0 / 60.0);
    const double alpha = (rr - 1.0) / (rr + 1.0);
    const double len   = (1.0 / alpha) * (double)SRATE / (freq + 30.0 / alpha);
    const int    nk    = (int)floor(len);
    const int    s     = (NFFT - nk) / 2;
    const int    k0    = s & ~(BK2 - 1);
    int          k1    = (s + nk + BK2 - 1) & ~(BK2 - 1);
    if (k1 > NFFT) k1 = NFFT;
    const int nsteps = (k1 - k0) >> 6;

    const int t    = threadIdx.x;
    const int lane = t & 63;
    const int w    = t >> 6;
    const int wr   = w >> 1, wc = w & 1;
    const int l15  = lane & 15, kq = lane >> 4;

    // staging source pointers: thread t stages chunks c = t + 256p
    const __hip_bfloat16* srcA[4];
    const __hip_bfloat16* srcB[4];
    #pragma unroll
    for (int p = 0; p < 4; ++p) {
        const int c   = t + 256 * p;
        const int lr  = c >> 3;                       // local row 0..127
        const int kc  = c & 7;
        int row = row0 + lr;
        if (row > MROWS - 1) row = MROWS - 1;
        const int bb = row / NFRAMES;
        const int ff = row - bb * NFRAMES;
        srcA[p] = xp + (size_t)bb * XPITCH + (size_t)ff * HOPSZ
                     + ((kc ^ (lr & 7)) << 3) + k0;
        srcB[p] = tab + (size_t)(n0 + lr) * NFFT + (kc << 3) + k0;  // tab pre-swizzled
    }

    f32x4 acc[4][4] = {};

    // STAGE(buf): 4 A + 4 B global_load_lds (16B/lane), then advance K
    #define STAGE(BUF)                                                            \
        do {                                                                      \
            const int cb = (BUF) * 2048;                                          \
            _Pragma("unroll")                                                     \
            for (int p = 0; p < 4; ++p) {                                         \
                __builtin_amdgcn_global_load_lds((const void*)srcA[p],            \
                    (void*)&smem4[cb + p * 256 + w * 64], 16, 0, 0);              \
                srcA[p] += BK2;                                                   \
            }                                                                     \
            _Pragma("unroll")                                                     \
            for (int p = 0; p < 4; ++p) {                                         \
                __builtin_amdgcn_global_load_lds((const void*)srcB[p],            \
                    (void*)&smem4[cb + 1024 + p * 256 + w * 64], 16, 0, 0);       \
                srcB[p] += BK2;                                                   \
            }                                                                     \
        } while (0)

    STAGE(0);
    __syncthreads();

    int buf = 0;
    for (int step = 0; step < nsteps; ++step) {
        if (step + 1 < nsteps) STAGE(buf ^ 1);
        const char* Ab = (const char*)smem4 + buf * 32768;
        const char* Bb = Ab + 16384;
        #pragma unroll
        for (int ks = 0; ks < 2; ++ks) {
            const int ko = ks * 32 + kq * 8;
            short8 af[4], bf[4];
            #pragma unroll
            for (int i = 0; i < 4; ++i) af[i] = lds_frag(Ab, wr * 64 + i * 16 + l15, ko);
            #pragma unroll
            for (int j = 0; j < 4; ++j) bf[j] = lds_frag(Bb, wc * 64 + j * 16 + l15, ko);
            #pragma unroll
            for (int i = 0; i < 4; ++i)
                #pragma unroll
                for (int j = 0; j < 4; ++j)
                    acc[i][j] = __builtin_amdgcn_mfma_f32_16x16x32_bf16(af[i], bf[j], acc[i][j], 0, 0, 0);
        }
        __syncthreads();
        buf ^= 1;
    }
    #undef STAGE

    // ---- epilogue: mag of (re,im) lane pairs, compacted to 16 bins/16 lanes
    const int rowb = row0 + wr * 64;
    const int binb = (n0 + wc * 64) >> 1;
    const int lbase = lane & 48;
    const int srcl  = lbase | ((l15 & 7) << 1);
    #pragma unroll
    for (int i = 0; i < 4; ++i) {
        #pragma unroll
        for (int jp = 0; jp < 2; ++jp) {
            #pragma unroll
            for (int reg = 0; reg < 4; ++reg) {
                const float v0 = acc[i][2 * jp][reg];
                const float v1 = acc[i][2 * jp + 1][reg];
                const float p0 = __shfl_xor(v0, 1);
                const float p1 = __shfl_xor(v1, 1);
                const float m0 = sqrtf(v0 * v0 + p0 * p0);
                const float m1 = sqrtf(v1 * v1 + p1 * p1);
                const float r0 = __shfl(m0, srcl);
                const float r1 = __shfl(m1, srcl);
                const float m  = (l15 < 8) ? r0 : r1;
                const int row = rowb + i * 16 + kq * 4 + reg;
                const int bin = binb + jp * 16 + l15;
                if (row < MROWS && bin < NBINS)
                    out[(size_t)row * NBINS + bin] = m;
            }
        }
    }
}

// ======================= PATH B fallback: round-2 kernel ====================
#define NPADB   544
#define NCOLS   1088
#define BM 64
#define BN 64
#define BK 64
#define MTILES 7
#define NTILES 17
#define APITCH 72

__global__ void build_tab(__hip_bfloat16* __restrict__ tab) {
    const int bin = blockIdx.x;
    __hip_bfloat16* rowre = tab + (size_t)(2 * bin) * NFFT;
    __hip_bfloat16* rowim = rowre + NFFT;
    if (bin >= NBINS) {
        const __hip_bfloat16 z = __float2bfloat16(0.f);
        for (int t = threadIdx.x; t < NFFT; t += blockDim.x) { rowre[t] = z; rowim[t] = z; }
        return;
    }
    const double freq  = 27.5 * exp2((double)bin / 60.0);
    const double r     = exp2(2.0 / 60.0);
    const double alpha = (r - 1.0) / (r + 1.0);
    const double len   = (1.0 / alpha) * (double)SRATE / (freq + 30.0 / alpha);
    const int    nk    = (int)floor(len);
    const int    s     = (NFFT - nk) / 2;
    const double amp   = (2.0 / (double)(nk - 1)) / sqrt(len);
    for (int t = threadIdx.x; t < NFFT; t += blockDim.x) {
        float re = 0.f, im = 0.f;
        const int tp = t - s;
        if (tp >= 0 && tp < nk) {
            const double w  = 0.5 - 0.5 * cos(2.0 * PI_D * (double)tp / (double)(nk - 1));
            const double ph = fmod(2.0 * freq * (double)tp / (double)SRATE, 2.0);
            double sp, cp;
            sincospi(ph, &sp, &cp);
            re = (float)(w * amp * cp);
            im = (float)(-w * amp * sp);
        }
        rowre[t] = __float2bfloat16(re);
        rowim[t] = __float2bfloat16(im);
    }
}

__global__ __launch_bounds__(256) void vqt_gemm(const float* __restrict__ x,
                                                const __hip_bfloat16* __restrict__ tab,
                                                float* __restrict__ out) {
    __shared__ __hip_bfloat16 As[BM * APITCH];
    __shared__ __hip_bfloat16 Bs[BN * APITCH];
    const int mt = blockIdx.x, nt = blockIdx.y, b = blockIdx.z;
    const int n0 = nt * BN;
    const int    bin0  = n0 >> 1;
    const double freq  = 27.5 * exp2((double)bin0 / 60.0);
    const double r     = exp2(2.0 / 60.0);
    const double alpha = (r - 1.0) / (r + 1.0);
    const double len   = (1.0 / alpha) * (double)SRATE / (freq + 30.0 / alpha);
    const int    nk    = (int)floor(len);
    const int    s     = (NFFT - nk) / 2;
    const int    k0    = s & ~(BK - 1);
    int          k1    = (s + nk + BK - 1) & ~(BK - 1);
    if (k1 > NFFT) k1 = NFFT;
    const int tid  = threadIdx.x;
    const int lane = tid & 63;
    const int wid  = tid >> 6;
    const int wr   = wid >> 1, wc = wid & 1;
    const int sr   = tid >> 2, sq = tid & 3;
    const float* xb     = x + (size_t)b * NSAMP;
    const int    f_base = mt * BM;
    const long arow_off = (long)(f_base + sr) * HOPSZ - PADW + sq * 16;
    const __hip_bfloat16* brow = tab + (size_t)(n0 + sr) * NFFT + sq * 16;
    f32x4 acc[2][2] = {};
    for (int kt = k0; kt < k1; kt += BK) {
        union { short8 v[2]; unsigned short u[16]; } pk;
        #pragma unroll
        for (int v = 0; v < 4; ++v) {
            const long g = arow_off + kt + v * 4;
            float4 t4 = {0.f, 0.f, 0.f, 0.f};
            if (g >= 0 && g + 4 <= (long)NSAMP) t4 = *(const float4*)(xb + g);
            __hip_bfloat16 h0 = __float2bfloat16(t4.x);
            __hip_bfloat16 h1 = __float2bfloat16(t4.y);
            __hip_bfloat16 h2 = __float2bfloat16(t4.z);
            __hip_bfloat16 h3 = __float2bfloat16(t4.w);
            pk.u[4 * v + 0] = *(unsigned short*)&h0;
            pk.u[4 * v + 1] = *(unsigned short*)&h1;
            pk.u[4 * v + 2] = *(unsigned short*)&h2;
            pk.u[4 * v + 3] = *(unsigned short*)&h3;
        }
        { short8* dst = (short8*)(As + sr * APITCH + sq * 16); dst[0] = pk.v[0]; dst[1] = pk.v[1]; }
        { const short8* src = (const short8*)(brow + kt);
          short8* dst = (short8*)(Bs + sr * APITCH + sq * 16); dst[0] = src[0]; dst[1] = src[1]; }
        __syncthreads();
        #pragma unroll
        for (int ks = 0; ks < 2; ++ks) {
            const int kc = ks * 32 + (lane >> 4) * 8;
            const short8 a0 = *(const short8*)(As + (wr * 32 +      (lane & 15)) * APITCH + kc);
            const short8 a1 = *(const short8*)(As + (wr * 32 + 16 + (lane & 15)) * APITCH + kc);
            const short8 b0 = *(const short8*)(Bs + (wc * 32 +      (lane & 15)) * APITCH + kc);
            const short8 b1 = *(const short8*)(Bs + (wc * 32 + 16 + (lane & 15)) * APITCH + kc);
            acc[0][0] = __builtin_amdgcn_mfma_f32_16x16x32_bf16(a0, b0, acc[0][0], 0, 0, 0);
            acc[0][1] = __builtin_amdgcn_mfma_f32_16x16x32_bf16(a0, b1, acc[0][1], 0, 0, 0);
            acc[1][0] = __builtin_amdgcn_mfma_f32_16x16x32_bf16(a1, b0, acc[1][0], 0, 0, 0);
            acc[1][1] = __builtin_amdgcn_mfma_f32_16x16x32_bf16(a1, b1, acc[1][1], 0, 0, 0);
        }
        __syncthreads();
    }
    const int colc = lane & 15, rg = lane >> 4;
    float* outb = out + (size_t)b * NFRAMES * NBINS;
    #pragma unroll
    for (int i = 0; i < 2; ++i)
        #pragma unroll
        for (int j = 0; j < 2; ++j)
            #pragma unroll
            for (int reg = 0; reg < 4; ++reg) {
                const float v = acc[i][j][reg];
                const float p = __shfl_xor(v, 1);
                if (!(lane & 1)) {
                    const int f   = f_base + wr * 32 + i * 16 + rg * 4 + reg;
                    const int col = n0 + wc * 32 + j * 16 + colc;
                    const int bin = col >> 1;
                    if (f < NFRAMES && bin < NBINS)
                        outb[(size_t)f * NBINS + bin] = sqrtf(v * v + p * p);
                }
            }
}

extern "C" void kernel_launch(void* const* d_in, const int* in_sizes, int n_in,
                              void* d_out, int out_size, void* d_ws, size_t ws_size,
                              hipStream_t stream) {
    const float* x = (const float*)d_in[0];
    float* out = (float*)d_out;
    const size_t needA = (size_t)(XPTOT + (size_t)NCOLS2 * NFFT) * 2;   // 11,840,256 B
    const size_t needB = (size_t)NCOLS * NFFT * sizeof(__hip_bfloat16); // 4.46 MB
    if (ws_size >= needA) {
        __hip_bfloat16* xp  = (__hip_bfloat16*)d_ws;
        __hip_bfloat16* tab = xp + XPTOT;
        cvt_xp<<<dim3((NBATCH * NCHUNK + 255) / 256), dim3(256), 0, stream>>>(x, xp);
        build_tab_swz<<<dim3(NCOLS2), dim3(256), 0, stream>>>(tab);
        vqt_gemm2<<<dim3(MT2, NT2), dim3(256), 0, stream>>>(xp, tab, out);
    } else if (ws_size >= needB) {
        build_tab<<<dim3(NPADB), dim3(256), 0, stream>>>((__hip_bfloat16*)d_ws);
        vqt_gemm<<<dim3(MTILES, NTILES, NBATCH), dim3(256), 0, stream>>>(
            x, (const __hip_bfloat16*)d_ws, out);
    }
}